// Round 6
// baseline (1201.576 us; speedup 1.0000x reference)
//
#include <hip/hip_runtime.h>
#include <cstdint>
#include <cstddef>

// Problem constants (fixed by reference)
#define N_SEQ 64
#define T_LEN 256
#define VOCAB 32000
#define EDIM  256
#define KS    128          // hidden states
#define KK    16384        // KS*KS
#define MROWS 16384        // padded (t,n) rows for GEMM (real: 255*64 = 16320)
#define MREAL 16320
#define GPART 32           // srow partial groups (by-split in gemm grid)

typedef short  short8  __attribute__((ext_vector_type(8)));
typedef float  floatx4 __attribute__((ext_vector_type(4)));
typedef int    intx8   __attribute__((ext_vector_type(8)));

#define LGKM_BARRIER() asm volatile("s_waitcnt lgkmcnt(0)\n\ts_barrier" ::: "memory")
#define LGKM_WAIT()    asm volatile("s_waitcnt lgkmcnt(0)" ::: "memory")
// raw barrier with LDS-only drain: does NOT drain vmcnt (prefetches ride across)
#define SBAR() do { asm volatile("s_waitcnt lgkmcnt(0)" ::: "memory"); \
                    __builtin_amdgcn_s_barrier(); \
                    __builtin_amdgcn_sched_barrier(0); } while (0)

static __device__ __forceinline__ unsigned short f2bf(float f) {
  unsigned u = __float_as_uint(f);
  u += 0x7fffu + ((u >> 16) & 1u);          // RNE
  return (unsigned short)(u >> 16);
}

static __device__ __forceinline__ float bf2f(unsigned short h) {
  return __uint_as_float(((unsigned)h) << 16);
}

static __device__ __forceinline__ float fast_rcp(float x) {
#if __has_builtin(__builtin_amdgcn_rcpf)
  return __builtin_amdgcn_rcpf(x);
#else
  return 1.0f / x;
#endif
}

static __device__ __forceinline__ void gl_lds16(const void* gptr, void* lptr) {
  __builtin_amdgcn_global_load_lds(
      (const __attribute__((address_space(1))) void*)gptr,
      (__attribute__((address_space(3))) void*)lptr, 16, 0, 0);
}

// ---------------- start-distribution log_softmax -------------------------
__global__ __launch_bounds__(128) void k_prep(const float* sw, const float* sb, float* pre0) {
  __shared__ float vals[KS];
  __shared__ float MM, LS;
  int tid = threadIdx.x;
  float v = sw[tid] + sb[tid];
  vals[tid] = v;
  __syncthreads();
  if (tid == 0) { float m = vals[0]; for (int i = 1; i < KS; ++i) m = fmaxf(m, vals[i]); MM = m; }
  __syncthreads();
  float e = __expf(v - MM);
  vals[tid] = e;
  __syncthreads();
  if (tid == 0) { float s = 0.f; for (int i = 0; i < KS; ++i) s += vals[i]; LS = MM + __logf(s); }
  __syncthreads();
  pre0[tid] = v - LS;
}

// ------- trans_w fp32 -> bf16, ROW-PERMUTED row'=(j)*128+(i), k-SWIZZLED -
__global__ __launch_bounds__(256) void k_transcvt(const float* tw, unsigned short* tb) {
  int idx = blockIdx.x * 256 + threadIdx.x;          // over float4 groups
  if (idx >= (KK * EDIM) / 4) return;
  int row = idx >> 6, e4 = idx & 63;
  int rowp = ((row & 127) << 7) | (row >> 7);
  int e4s = (e4 & 0x31) | (((((e4 >> 1) & 7) ^ (rowp & 7))) << 1);
  float4 v = *(const float4*)&tw[(size_t)idx * 4];
  unsigned h0 = f2bf(v.x), h1 = f2bf(v.y), h2 = f2bf(v.z), h3 = f2bf(v.w);
  uint2 o; o.x = h0 | (h1 << 16); o.y = h2 | (h3 << 16);
  *(uint2*)&tb[(size_t)rowp * EDIM + e4s * 4] = o;
}

// ------- gather token embeddings -> bf16 rows m = t*64+n, k-SWIZZLED -----
__global__ __launch_bounds__(256) void k_embed(const int* x, const float* ew, unsigned short* exb) {
  int m = blockIdx.x, e = threadIdx.x;
  int t = m >> 6, n = m & 63;
  float v = 0.f;
  if (m < MREAL) { int tok = x[n * T_LEN + t]; v = ew[(size_t)tok * EDIM + e]; }
  int es = (e & 0xC7) | ((((e >> 3) & 7) ^ (m & 7)) << 3);
  exb[(size_t)m * EDIM + es] = f2bf(v);
}

// ---------------- emission logits C[k][v] = ecl[k] . emit_w[v] -----------
__global__ __launch_bounds__(256) void k_emitlogits(const float* ecl, const float* emw, float* C) {
  int v0 = blockIdx.x * 64, k0 = blockIdx.y * 64;
  int tid = threadIdx.x;
  __shared__ alignas(16) float At[64 * 17];
  __shared__ alignas(16) float Bt[64 * 17];
  int tx = tid & 15, ty = tid >> 4;
  int r = tid >> 2, q = tid & 3;
  float acc[4][4] = {};
  for (int d0 = 0; d0 < KS; d0 += 16) {
    float4 av = *(const float4*)&ecl[(size_t)(k0 + r) * KS + d0 + q * 4];
    float4 bv = *(const float4*)&emw[(size_t)(v0 + r) * KS + d0 + q * 4];
    __syncthreads();
    At[r * 17 + q * 4 + 0] = av.x; At[r * 17 + q * 4 + 1] = av.y;
    At[r * 17 + q * 4 + 2] = av.z; At[r * 17 + q * 4 + 3] = av.w;
    Bt[r * 17 + q * 4 + 0] = bv.x; Bt[r * 17 + q * 4 + 1] = bv.y;
    Bt[r * 17 + q * 4 + 2] = bv.z; Bt[r * 17 + q * 4 + 3] = bv.w;
    __syncthreads();
    #pragma unroll
    for (int dd = 0; dd < 16; ++dd) {
      float a[4], b[4];
      #pragma unroll
      for (int i = 0; i < 4; ++i) a[i] = At[(ty * 4 + i) * 17 + dd];
      #pragma unroll
      for (int i = 0; i < 4; ++i) b[i] = Bt[(tx * 4 + i) * 17 + dd];
      #pragma unroll
      for (int i = 0; i < 4; ++i)
        #pragma unroll
        for (int jj = 0; jj < 4; ++jj) acc[i][jj] += a[i] * b[jj];
    }
  }
  #pragma unroll
  for (int i = 0; i < 4; ++i) {
    float4 o; o.x = acc[i][0]; o.y = acc[i][1]; o.z = acc[i][2]; o.w = acc[i][3];
    *(float4*)&C[(size_t)(k0 + ty * 4 + i) * VOCAB + v0 + tx * 4] = o;
  }
}

// ---------------- per-cluster lse over vocab -----------------------------
__global__ __launch_bounds__(256) void k_lsec(const float* C, float* lseC) {
  int k = blockIdx.x, tid = threadIdx.x;
  __shared__ float sm[4], ss[4];
  const float* row = C + (size_t)k * VOCAB;
  float m = -1e30f;
  for (int v = tid; v < VOCAB; v += 256) m = fmaxf(m, row[v]);
  #pragma unroll
  for (int s = 1; s < 64; s <<= 1) m = fmaxf(m, __shfl_xor(m, s));
  if ((tid & 63) == 0) sm[tid >> 6] = m;
  __syncthreads();
  m = fmaxf(fmaxf(sm[0], sm[1]), fmaxf(sm[2], sm[3]));
  float sum = 0.f;
  for (int v = tid; v < VOCAB; v += 256) sum += __expf(row[v] - m);
  #pragma unroll
  for (int s = 1; s < 64; s <<= 1) sum += __shfl_xor(sum, s);
  if ((tid & 63) == 0) ss[tid >> 6] = sum;
  __syncthreads();
  if (tid == 0) lseC[k] = m + __logf(ss[0] + ss[1] + ss[2] + ss[3]);
}

// ------- gather emission log-probs emis[n][t][k] + per-(n,t) max ---------
__global__ __launch_bounds__(128) void k_emis(const int* x, const float* C, const float* lseC,
                                              float* emis, float* emax) {
  int t = blockIdx.x + 1;          // 1..255
  int n = blockIdx.y;
  int k = threadIdx.x;
  __shared__ float red[2];
  int w = x[n * T_LEN + t];
  float v = C[(size_t)k * VOCAB + w] - lseC[k];
  emis[(size_t)((n << 8) + t) * KS + k] = v;
  float m = v;
  #pragma unroll
  for (int s = 1; s < 64; s <<= 1) m = fmaxf(m, __shfl_xor(m, s));
  if ((k & 63) == 0) red[k >> 6] = m;
  __syncthreads();
  if (k == 0) emax[n * T_LEN + t] = fmaxf(red[0], red[1]);
}

// ---- combine srow partials (bf16) -> srowR[m][i] = 1/sum  AND the fused
//      scan weight wcomb[m][i] = exp(emis - emax) * srowR * 4096 ----------
__global__ __launch_bounds__(256) void k_comb(const unsigned short* srowPh, float* srowR, float* wcomb,
                                              const float* emis, const float* emax,
                                              int m_base, int Rcap, int rows) {
  int id = blockIdx.x * 256 + threadIdx.x;
  if (id >= rows * KS) return;
  float s = 0.f;
  #pragma unroll
  for (int g = 0; g < GPART; ++g) s += bf2f(srowPh[(size_t)g * Rcap * KS + id]);
  float r = 1.0f / s;
  srowR[(size_t)m_base * KS + id] = r;
  int m = m_base + (id >> 7);
  int t = m >> 6, n = m & 63, k = id & 127;
  float wv = 0.f;
  if (t >= 1) {               // t==0 rows: emis/emax uninitialized, w never read
    float e  = emis[(size_t)((n << 8) + t) * KS + k];
    float ex = emax[n * T_LEN + t];
    wv = __expf(e - ex) * r * 4096.0f;
  }
  wcomb[(size_t)m_base * KS + id] = wv;
}

// ---- load one wave's q-slice of S(t): rows j, bytes kg*32 ---------------
static __device__ __forceinline__ void load_S2(const unsigned char* Sbase, int j, int kg, intx8& sf) {
  const uint4* p = (const uint4*)(Sbase + (size_t)j * 128 + kg * 32);
  uint4 a = p[0], b = p[1];
  sf[0] = a.x; sf[1] = a.y; sf[2] = a.z; sf[3] = a.w;
  sf[4] = b.x; sf[5] = b.y; sf[6] = b.z; sf[7] = b.w;
}

// ---- 4-wave scan step: wave w owns MFMA q in {2w, 2w+1} (r5 structure) --
static __device__ __forceinline__ void scan_step4(
    int i, int L, int t, int t0s, int tLast, int n, int tid, int kg, int j0, int j1,
    const unsigned char* Ss, const float* wcomb, const float* emis, const float* emax,
    unsigned char* uL8, float* c0sh,
    intx8& uf, intx8& s0, intx8& s1, float& w0, float& w1, float& ex,
    float& M, float& pre_0, float& pre_1) {
  const float LNS = 8.317766167f;              // ln(4096)
  floatx4 cz = {0.f, 0.f, 0.f, 0.f};
  floatx4 d0 = __builtin_amdgcn_mfma_scale_f32_16x16x128_f8f6f4(
      uf, s0, cz, 0, 0, 0, 0x7F7F7F7F, 0, 0x7F7F7F7F);
  floatx4 d1 = __builtin_amdgcn_mfma_scale_f32_16x16x128_f8f6f4(
      uf, s1, cz, 0, 0, 0, 0x7F7F7F7F, 0, 0x7F7F7F7F);
  float cv0 = d0[0], cv1 = d1[0];
  // prefetch this wave's S(t+2) slice into the just-consumed regs
  int tp = t + 2; if (tp > tLast) tp = tLast;
  const unsigned char* Sp = Ss + (size_t)((tp - t0s) * 64 + n) * KK;
  load_S2(Sp, j0, kg, s0);
  load_S2(Sp, j1, kg, s1);
  if (tid == 0) *c0sh = cv0;                   // j0==0 on thread 0
  SBAR();                                      // c0 visible
  if (i < L - 1) {
    float c0 = *c0sh;
    float rc = fast_rcp(c0);
    float u0 = cv0 * w0 * rc, u1 = cv1 * w1 * rc;
    int pk0 = __builtin_amdgcn_cvt_pk_fp8_f32(u0, u0, 0, 0);
    int pk1 = __builtin_amdgcn_cvt_pk_fp8_f32(u1, u1, 0, 0);
    if (kg == 0) {
      uL8[j0] = (unsigned char)(pk0 & 0xff);
      uL8[j1] = (unsigned char)(pk1 & 0xff);
    }
    M += ex + __logf(c0) - LNS;                // wave-uniform, off u-chain
    // prefetch w/ex (t+2) — ride across barriers
    w0 = wcomb[(size_t)(tp * 64 + n) * KS + j0];
    w1 = wcomb[(size_t)(tp * 64 + n) * KS + j1];
    ex = emax[n * T_LEN + tp];
    SBAR();                                    // uL8(t+1) visible
    uint4 ua = *(const uint4*)&uL8[kg * 32];
    uint4 ub = *(const uint4*)&uL8[kg * 32 + 16];
    uf[0] = ua.x; uf[1] = ua.y; uf[2] = ua.z; uf[3] = ua.w;
    uf[4] = ub.x; uf[5] = ub.y; uf[6] = ub.z; uf[7] = ub.w;
  } else {
    float em0 = emis[(size_t)((n << 8) + tLast) * KS + j0];
    float em1 = emis[(size_t)((n << 8) + tLast) * KS + j1];
    pre_0 = M - LNS + __logf(cv0) + em0;
    pre_1 = M - LNS + __logf(cv1) + em1;
    SBAR();                                    // uniform barrier count
  }
}

// ---- FUSED kernel: blocks [0,64) = scan of chunk c-1 (4 waves/block);
//      blocks [64, 64+gx*32) = GEMM of chunk c (4 bys/block, 32 groups). --
__global__ __launch_bounds__(256, 4) void k_fused(
    const unsigned short* exb, const unsigned short* trb,
    unsigned char* Sg, unsigned short* srowPh, int m_base, int Rcap,
    const unsigned char* Ss, const float* srowR, const float* wcomb,
    const float* emis, const float* emax, const float* pre0,
    float* alphaG, float* nll, int t0s, int tcs) {
  __shared__ alignas(16) unsigned short As[128 * 64];
  __shared__ alignas(16) unsigned short Bs[128 * 64];
  __shared__ alignas(16) unsigned char uL8[KS];
  __shared__ float c0sh;
  __shared__ float redW[4], redE[4];

  if (blockIdx.x < 64) {
    // -------- scan path: all 4 waves cooperate, uniform control flow -----
    if (tcs <= 0) return;
    int n = blockIdx.x;
    int tid = threadIdx.x;
    int w = tid >> 6, ln = tid & 63;
    int l15 = ln & 15, kg = ln >> 4;
    int q0 = w * 2;
    int j0 = q0 * 16 + l15, j1 = j0 + 16;
    const float SCALE = 4096.0f;
    int L = tcs, t1 = t0s + tcs, tLast = t1 - 1;
    const float* a0 = (t0s == 1) ? pre0 : (alphaG + (size_t)n * KS);
    float pre_0 = a0[j0], pre_1 = a0[j1];
    // cross-wave max for M
    float lm = fmaxf(pre_0, pre_1);
    #pragma unroll
    for (int s2 = 1; s2 < 16; s2 <<= 1) lm = fmaxf(lm, __shfl_xor(lm, s2));
    if (ln == 0) redW[w] = lm;
    SBAR();
    float M = fmaxf(fmaxf(redW[0], redW[1]), fmaxf(redW[2], redW[3]));
    // u(t0) from log-domain handoff
    {
      float r0 = srowR[(size_t)((t0s - 1) * 64 + n) * KS + j0];
      float r1 = srowR[(size_t)((t0s - 1) * 64 + n) * KS + j1];
      float u0 = __expf(pre_0 - M) * r0 * SCALE;
      float u1 = __expf(pre_1 - M) * r1 * SCALE;
      int pk0 = __builtin_amdgcn_cvt_pk_fp8_f32(u0, u0, 0, 0);
      int pk1 = __builtin_amdgcn_cvt_pk_fp8_f32(u1, u1, 0, 0);
      if (kg == 0) {
        uL8[j0] = (unsigned char)(pk0 & 0xff);
        uL8[j1] = (unsigned char)(pk1 & 0xff);
      }
    }
    SBAR();
    intx8 uf;
    {
      uint4 ua = *(const uint4*)&uL8[kg * 32];
      uint4 ub = *(const uint4*)&uL8[kg * 32 + 16];
      uf[0] = ua.x; uf[1] = ua.y; uf[2] = ua.z; uf[3] = ua.w;
      uf[4] = ub.x; uf[5] = ub.y; uf[6] = ub.z; uf[7] = ub.w;
    }
    // prime double-buffered per-wave state
    intx8 sA0, sA1, sB0, sB1;
    load_S2(Ss + (size_t)n * KK, j0, kg, sA0);
    load_S2(Ss + (size_t)n * KK, j1, kg, sA1);
    int iB = (L > 1) ? 1 : 0;
    const unsigned char* SpB = Ss + (size_t)(iB * 64 + n) * KK;
    load_S2(SpB, j0, kg, sB0);
    load_S2(SpB, j1, kg, sB1);
    int tB = t0s + iB;
    float wA0 = wcomb[(size_t)(t0s * 64 + n) * KS + j0];
    float wA1 = wcomb[(size_t)(t0s * 64 + n) * KS + j1];
    float wB0 = wcomb[(size_t)(tB * 64 + n) * KS + j0];
    float wB1 = wcomb[(size_t)(tB * 64 + n) * KS + j1];
    float exA = emax[n * T_LEN + t0s];
    float exB = emax[n * T_LEN + tB];
    int i = 0, t = t0s;
    for (;;) {
      scan_step4(i, L, t, t0s, tLast, n, tid, kg, j0, j1, Ss, wcomb, emis, emax,
                 uL8, &c0sh, uf, sA0, sA1, wA0, wA1, exA, M, pre_0, pre_1);
      if (++i >= L) break; ++t;
      scan_step4(i, L, t, t0s, tLast, n, tid, kg, j0, j1, Ss, wcomb, emis, emax,
                 uL8, &c0sh, uf, sB0, sB1, wB0, wB1, exB, M, pre_0, pre_1);
      if (++i >= L) break; ++t;
    }
    if (kg == 0) {
      alphaG[(size_t)n * KS + j0] = pre_0;
      alphaG[(size_t)n * KS + j1] = pre_1;
    }
    if (t1 == T_LEN) {
      float m2 = fmaxf(pre_0, pre_1);
      #pragma unroll
      for (int s2 = 1; s2 < 16; s2 <<= 1) m2 = fmaxf(m2, __shfl_xor(m2, s2));
      if (ln == 0) redW[w] = m2;
      SBAR();
      m2 = fmaxf(fmaxf(redW[0], redW[1]), fmaxf(redW[2], redW[3]));
      float le = __expf(pre_0 - m2) + __expf(pre_1 - m2);
      #pragma unroll
      for (int s2 = 1; s2 < 16; s2 <<= 1) le += __shfl_xor(le, s2);
      if (ln == 0) redE[w] = le;
      SBAR();
      if (tid == 0) nll[n] = m2 + __logf(redE[0] + redE[1] + redE[2] + redE[3]);
    }
    return;
  }

  // ---------------- GEMM path: 4 bys/block, 32 partial groups -----------
  int g = blockIdx.x - 64;
  int bx = g >> 5, grp = g & 31;
  int tid = threadIdx.x, wv = tid >> 6, ln = tid & 63;
  int wc = wv & 1, wm = wv >> 1;
  int m0 = m_base + bx * 128;
  int lr = ln & 15, lk = (ln >> 4) * 8;
  int lg = ln >> 4;
  floatx4 sacc[4][4] = {};
  for (int byi = 0; byi < 4; ++byi) {
    int by = grp * 4 + byi;
    int c0 = by * 128;
    floatx4 acc[4][4] = {};
    for (int k0 = 0; k0 < EDIM; k0 += 64) {
      #pragma unroll
      for (int r = 0; r < 4; ++r) {
        int chunk = (wv * 4 + r) * 64 + ln;
        int row = chunk >> 3, c8 = chunk & 7;
        gl_lds16(&exb[(size_t)(m0 + row) * EDIM + k0 + c8 * 8], &As[(wv * 4 + r) * 512]);
        gl_lds16(&trb[(size_t)(c0 + row) * EDIM + k0 + c8 * 8], &Bs[(wv * 4 + r) * 512]);
      }
      __syncthreads();                         // staging arrival (vmcnt drain)
      #pragma unroll
      for (int kk = 0; kk < 64; kk += 32) {
        int sw = ((((kk + lk) >> 3) ^ (lr & 7)) << 3);
        short8 af[4], bf[4];
        #pragma unroll
        for (int f = 0; f < 4; ++f)
          af[f] = *(const short8*)&As[(wm * 64 + f * 16 + lr) * 64 + sw];
        #pragma unroll
        for (int f = 0; f < 4; ++f)
          bf[f] = *(const short8*)&Bs[(wc * 64 + f * 16 + lr) * 64 + sw];
        #pragma unroll
        for (int fc = 0; fc < 4; ++fc)
          #pragma unroll
          for (int fm = 0; fm < 4; ++fm)
            acc[fc][fm] = __builtin_amdgcn_mfma_f32_16x16x32_bf16(bf[fc], af[fm], acc[fc][fm], 0, 0, 0);
      }
      LGKM_BARRIER();
    }
    unsigned char* Ts = (unsigned char*)As;
    #pragma unroll
    for (int fc = 0; fc < 4; ++fc) {
      #pragma unroll
      for (int fm = 0; fm < 4; ++fm) {
        floatx4 a = acc[fc][fm];
        float e0 = __expf(a[0]), e1 = __expf(a[1]), e2 = __expf(a[2]), e3 = __expf(a[3]);
        int pq = __builtin_amdgcn_cvt_pk_fp8_f32(e0, e1, 0, 0);
        pq = __builtin_amdgcn_cvt_pk_fp8_f32(e2, e3, pq, 1);
        int mloc = wm * 64 + fm * 16 + lr;
        int cl = wc * 64 + fc * 16 + lg * 4;
        *(int*)&Ts[mloc * 128 + (cl ^ ((mloc & 7) << 4))] = pq;
        sacc[fc][fm][0] += e0; sacc[fc][fm][1] += e1;
        sacc[fc][fm][2] += e2; sacc[fc][fm][3] += e3;
      }
    }
    LGKM_BARRIER();
    #pragma unroll
    for (int r = 0; r < 4; ++r) {
      int seg = r * 256 + tid;
      int mloc = seg >> 3, s = seg & 7;
      uint4 v = *(const uint4*)&Ts[mloc * 128 + ((s ^ (mloc & 7)) << 4)];
      *(uint4*)&Sg[(size_t)(bx * 128 + mloc) * KK + c0 + s * 16] = v;
    }
    LGKM_BARRIER();
  }
  // bf16 partial row-sums (32 groups, same bytes as 16 fp32 groups)
  #pragma unroll
  for (int fc = 0; fc < 4; ++fc) {
    #pragma unroll
    for (int fm = 0; fm < 4; ++fm) {
      int mloc = bx * 128 + wm * 64 + fm * 16 + lr;
      int i = wc * 64 + fc * 16 + lg * 4;
      ushort4 h;
      h.x = f2bf(sacc[fc][fm][0]); h.y = f2bf(sacc[fc][fm][1]);
      h.z = f2bf(sacc[fc][fm][2]); h.w = f2bf(sacc[fc][fm][3]);
      *(ushort4*)&srowPh[((size_t)grp * Rcap + mloc) * KS + i] = h;
    }
  }
}

// ---------------- final: out = -mean(nll) --------------------------------
__global__ __launch_bounds__(64) void k_final(const float* nll, float* out) {
  int tid = threadIdx.x;
  float v = nll[tid];
  #pragma unroll
  for (int s = 1; s < 64; s <<= 1) v += __shfl_xor(v, s);
  if (tid == 0) out[0] = -v / 64.0f;
}

extern "C" void kernel_launch(void* const* d_in, const int* in_sizes, int n_in,
                              void* d_out, int out_size, void* d_ws, size_t ws_size,
                              hipStream_t stream) {
  const int*   x       = (const int*)d_in[0];
  const float* embed_w = (const float*)d_in[1];
  const float* trans_w = (const float*)d_in[2];
  const float* start_w = (const float*)d_in[3];
  const float* start_b = (const float*)d_in[4];
  const float* ecl     = (const float*)d_in[5];
  const float* emw     = (const float*)d_in[6];

  char* w = (char*)d_ws;
  size_t off = 0;
  auto alloc = [&](size_t bytes) -> char* {
    char* p = w + off;
    off = (off + bytes + 255) & ~(size_t)255;
    return p;
  };
  float*          pre0   = (float*)alloc(KS * 4);
  float*          lseC   = (float*)alloc(KS * 4);
  float*          nll    = (float*)alloc(N_SEQ * 4);
  float*          alphaG = (float*)alloc((size_t)N_SEQ * KS * 4);
  float*          emax   = (float*)alloc((size_t)N_SEQ * T_LEN * 4);
  unsigned short* trb    = (unsigned short*)alloc((size_t)KK * EDIM * 2);
  unsigned short* exb    = (unsigned short*)alloc((size_t)MROWS * EDIM * 2);
  float*          emis   = (float*)alloc((size_t)N_SEQ * T_LEN * KS * 4);
  float*          srowR  = (float*)alloc((size_t)MROWS * KS * 4);
  float*          wcomb  = (float*)alloc((size_t)MROWS * KS * 4);
  // region: S double buffer + srowPh; transient C aliases region start
  char* region = w + off;
  size_t avail = (ws_size > off) ? (ws_size - off) : 0;
  float* C = (float*)region;

  // per chunk: R = Tc*64 rows; need 2*R*16384 (S dbuf) + R*8192 (srowPh:
  // 32 groups x 128 x bf16 = 8192 B/row — same budget as before)
  int Tc = 2;
  for (int c = 2; c <= 64; c += 2)
    if ((size_t)c * 64 * 40960 <= avail) Tc = c;
  int Rcap = Tc * 64;
  unsigned char*  S0     = (unsigned char*)region;
  unsigned char*  S1     = (unsigned char*)(region + (size_t)Rcap * KK);
  unsigned short* srowPh = (unsigned short*)(region + (size_t)2 * Rcap * KK);

  hipLaunchKernelGGL(k_prep,       dim3(1),        dim3(128), 0, stream, start_w, start_b, pre0);
  hipLaunchKernelGGL(k_transcvt,   dim3(4096),     dim3(256), 0, stream, trans_w, trb);
  hipLaunchKernelGGL(k_embed,      dim3(16384),    dim3(256), 0, stream, x, embed_w, exb);
  hipLaunchKernelGGL(k_emitlogits, dim3(500, 2),   dim3(256), 0, stream, ecl, emw, C);
  hipLaunchKernelGGL(k_lsec,       dim3(128),      dim3(256), 0, stream, C, lseC);
  hipLaunchKernelGGL(k_emis,       dim3(255, 64),  dim3(128), 0, stream, x, C, lseC, emis, emax);

  // chunk table
  int ct0[140], ctc[140], nc = 0;
  {
    int t0 = 1;
    while (t0 < T_LEN) {
      int tc = T_LEN - t0; if (tc > Tc) tc = Tc;
      ct0[nc] = t0; ctc[nc] = tc; ++nc; t0 += tc;
    }
  }
  // pipeline: fused_c = gemm(chunk c) + scan(chunk c-1); then comb(c)
  for (int c = 0; c <= nc; ++c) {
    bool hasG = (c < nc), hasS = (c > 0);
    int gx = 0, m_base = 0;
    if (hasG) { gx = (ctc[c] * 64 + 127) / 128; m_base = (ct0[c] - 1) * 64; }
    unsigned char* Sg = (c & 1) ? S1 : S0;
    unsigned char* Ssc = ((c - 1) & 1) ? S1 : S0;
    int t0s = hasS ? ct0[c - 1] : 0;
    int tcs = hasS ? ctc[c - 1] : 0;
    hipLaunchKernelGGL(k_fused, dim3(64 + gx * 32), dim3(256), 0, stream,
                       exb, trb, Sg, srowPh, m_base, Rcap,
                       Ssc, srowR, wcomb, emis, emax, pre0, alphaG, nll, t0s, tcs);
    if (hasG)
      hipLaunchKernelGGL(k_comb, dim3(gx * 64), dim3(256), 0, stream,
                         srowPh, srowR, wcomb, emis, emax, m_base, Rcap, gx * 128);
  }
  hipLaunchKernelGGL(k_final, dim3(1), dim3(64), 0, stream, nll, (float*)d_out);
}

// Round 7
// 532.901 us; speedup vs baseline: 2.2548x; 2.2548x over previous
//
#include <hip/hip_runtime.h>
#include <cstdint>
#include <cstddef>

// Problem constants (fixed by reference)
#define N_SEQ 64
#define T_LEN 256
#define VOCAB 32000
#define EDIM  256
#define KS    128          // hidden states
#define KK    16384        // KS*KS
#define MROWS 16384        // padded (t,n) rows for GEMM (real: 255*64 = 16320)
#define MREAL 16320
#define GPART 32           // srow partial groups (by-split in gemm grid)

typedef short  short8  __attribute__((ext_vector_type(8)));
typedef float  floatx4 __attribute__((ext_vector_type(4)));
typedef int    intx8   __attribute__((ext_vector_type(8)));

#define LGKM_BARRIER() asm volatile("s_waitcnt lgkmcnt(0)\n\ts_barrier" ::: "memory")
#define LGKM_WAIT()    asm volatile("s_waitcnt lgkmcnt(0)" ::: "memory")
// raw barrier with LDS-only drain: does NOT drain vmcnt (prefetches ride across)
#define SBAR() do { asm volatile("s_waitcnt lgkmcnt(0)" ::: "memory"); \
                    __builtin_amdgcn_s_barrier(); \
                    __builtin_amdgcn_sched_barrier(0); } while (0)

static __device__ __forceinline__ unsigned short f2bf(float f) {
  unsigned u = __float_as_uint(f);
  u += 0x7fffu + ((u >> 16) & 1u);          // RNE
  return (unsigned short)(u >> 16);
}

static __device__ __forceinline__ float bf2f(unsigned short h) {
  return __uint_as_float(((unsigned)h) << 16);
}

static __device__ __forceinline__ float fast_rcp(float x) {
#if __has_builtin(__builtin_amdgcn_rcpf)
  return __builtin_amdgcn_rcpf(x);
#else
  return 1.0f / x;
#endif
}

static __device__ __forceinline__ void gl_lds16(const void* gptr, void* lptr) {
  __builtin_amdgcn_global_load_lds(
      (const __attribute__((address_space(1))) void*)gptr,
      (__attribute__((address_space(3))) void*)lptr, 16, 0, 0);
}

// ---------------- start-distribution log_softmax -------------------------
__global__ __launch_bounds__(128) void k_prep(const float* sw, const float* sb, float* pre0) {
  __shared__ float vals[KS];
  __shared__ float MM, LS;
  int tid = threadIdx.x;
  float v = sw[tid] + sb[tid];
  vals[tid] = v;
  __syncthreads();
  if (tid == 0) { float m = vals[0]; for (int i = 1; i < KS; ++i) m = fmaxf(m, vals[i]); MM = m; }
  __syncthreads();
  float e = __expf(v - MM);
  vals[tid] = e;
  __syncthreads();
  if (tid == 0) { float s = 0.f; for (int i = 0; i < KS; ++i) s += vals[i]; LS = MM + __logf(s); }
  __syncthreads();
  pre0[tid] = v - LS;
}

// ------- trans_w fp32 -> bf16, ROW-PERMUTED row'=(j)*128+(i), k-SWIZZLED -
__global__ __launch_bounds__(256) void k_transcvt(const float* tw, unsigned short* tb) {
  int idx = blockIdx.x * 256 + threadIdx.x;          // over float4 groups
  if (idx >= (KK * EDIM) / 4) return;
  int row = idx >> 6, e4 = idx & 63;
  int rowp = ((row & 127) << 7) | (row >> 7);
  int e4s = (e4 & 0x31) | (((((e4 >> 1) & 7) ^ (rowp & 7))) << 1);
  float4 v = *(const float4*)&tw[(size_t)idx * 4];
  unsigned h0 = f2bf(v.x), h1 = f2bf(v.y), h2 = f2bf(v.z), h3 = f2bf(v.w);
  uint2 o; o.x = h0 | (h1 << 16); o.y = h2 | (h3 << 16);
  *(uint2*)&tb[(size_t)rowp * EDIM + e4s * 4] = o;
}

// ------- gather token embeddings -> bf16 rows m = t*64+n, k-SWIZZLED -----
__global__ __launch_bounds__(256) void k_embed(const int* x, const float* ew, unsigned short* exb) {
  int m = blockIdx.x, e = threadIdx.x;
  int t = m >> 6, n = m & 63;
  float v = 0.f;
  if (m < MREAL) { int tok = x[n * T_LEN + t]; v = ew[(size_t)tok * EDIM + e]; }
  int es = (e & 0xC7) | ((((e >> 3) & 7) ^ (m & 7)) << 3);
  exb[(size_t)m * EDIM + es] = f2bf(v);
}

// ---------------- emission logits C[k][v] = ecl[k] . emit_w[v] -----------
__global__ __launch_bounds__(256) void k_emitlogits(const float* ecl, const float* emw, float* C) {
  int v0 = blockIdx.x * 64, k0 = blockIdx.y * 64;
  int tid = threadIdx.x;
  __shared__ alignas(16) float At[64 * 17];
  __shared__ alignas(16) float Bt[64 * 17];
  int tx = tid & 15, ty = tid >> 4;
  int r = tid >> 2, q = tid & 3;
  float acc[4][4] = {};
  for (int d0 = 0; d0 < KS; d0 += 16) {
    float4 av = *(const float4*)&ecl[(size_t)(k0 + r) * KS + d0 + q * 4];
    float4 bv = *(const float4*)&emw[(size_t)(v0 + r) * KS + d0 + q * 4];
    __syncthreads();
    At[r * 17 + q * 4 + 0] = av.x; At[r * 17 + q * 4 + 1] = av.y;
    At[r * 17 + q * 4 + 2] = av.z; At[r * 17 + q * 4 + 3] = av.w;
    Bt[r * 17 + q * 4 + 0] = bv.x; Bt[r * 17 + q * 4 + 1] = bv.y;
    Bt[r * 17 + q * 4 + 2] = bv.z; Bt[r * 17 + q * 4 + 3] = bv.w;
    __syncthreads();
    #pragma unroll
    for (int dd = 0; dd < 16; ++dd) {
      float a[4], b[4];
      #pragma unroll
      for (int i = 0; i < 4; ++i) a[i] = At[(ty * 4 + i) * 17 + dd];
      #pragma unroll
      for (int i = 0; i < 4; ++i) b[i] = Bt[(tx * 4 + i) * 17 + dd];
      #pragma unroll
      for (int i = 0; i < 4; ++i)
        #pragma unroll
        for (int jj = 0; jj < 4; ++jj) acc[i][jj] += a[i] * b[jj];
    }
  }
  #pragma unroll
  for (int i = 0; i < 4; ++i) {
    float4 o; o.x = acc[i][0]; o.y = acc[i][1]; o.z = acc[i][2]; o.w = acc[i][3];
    *(float4*)&C[(size_t)(k0 + ty * 4 + i) * VOCAB + v0 + tx * 4] = o;
  }
}

// ---------------- per-cluster lse over vocab -----------------------------
__global__ __launch_bounds__(256) void k_lsec(const float* C, float* lseC) {
  int k = blockIdx.x, tid = threadIdx.x;
  __shared__ float sm[4], ss[4];
  const float* row = C + (size_t)k * VOCAB;
  float m = -1e30f;
  for (int v = tid; v < VOCAB; v += 256) m = fmaxf(m, row[v]);
  #pragma unroll
  for (int s = 1; s < 64; s <<= 1) m = fmaxf(m, __shfl_xor(m, s));
  if ((tid & 63) == 0) sm[tid >> 6] = m;
  __syncthreads();
  m = fmaxf(fmaxf(sm[0], sm[1]), fmaxf(sm[2], sm[3]));
  float sum = 0.f;
  for (int v = tid; v < VOCAB; v += 256) sum += __expf(row[v] - m);
  #pragma unroll
  for (int s = 1; s < 64; s <<= 1) sum += __shfl_xor(sum, s);
  if ((tid & 63) == 0) ss[tid >> 6] = sum;
  __syncthreads();
  if (tid == 0) lseC[k] = m + __logf(ss[0] + ss[1] + ss[2] + ss[3]);
}

// ------- gather emission log-probs emis[n][t][k] + per-(n,t) max ---------
__global__ __launch_bounds__(128) void k_emis(const int* x, const float* C, const float* lseC,
                                              float* emis, float* emax) {
  int t = blockIdx.x + 1;          // 1..255
  int n = blockIdx.y;
  int k = threadIdx.x;
  __shared__ float red[2];
  int w = x[n * T_LEN + t];
  float v = C[(size_t)k * VOCAB + w] - lseC[k];
  emis[(size_t)((n << 8) + t) * KS + k] = v;
  float m = v;
  #pragma unroll
  for (int s = 1; s < 64; s <<= 1) m = fmaxf(m, __shfl_xor(m, s));
  if ((k & 63) == 0) red[k >> 6] = m;
  __syncthreads();
  if (k == 0) emax[n * T_LEN + t] = fmaxf(red[0], red[1]);
}

// ---- combine srow partials (bf16) -> srowR[m][i] = 1/sum  AND the fused
//      scan weight wcomb[m][i] = exp(emis - emax) * srowR * 4096 ----------
__global__ __launch_bounds__(256) void k_comb(const unsigned short* srowPh, float* srowR, float* wcomb,
                                              const float* emis, const float* emax,
                                              int m_base, int Rcap, int rows) {
  int id = blockIdx.x * 256 + threadIdx.x;
  if (id >= rows * KS) return;
  float s = 0.f;
  #pragma unroll
  for (int g = 0; g < GPART; ++g) s += bf2f(srowPh[(size_t)g * Rcap * KS + id]);
  float r = 1.0f / s;
  srowR[(size_t)m_base * KS + id] = r;
  int m = m_base + (id >> 7);
  int t = m >> 6, n = m & 63, k = id & 127;
  float wv = 0.f;
  if (t >= 1) {               // t==0 rows: emis/emax uninitialized, w never read
    float e  = emis[(size_t)((n << 8) + t) * KS + k];
    float ex = emax[n * T_LEN + t];
    wv = __expf(e - ex) * r * 4096.0f;
  }
  wcomb[(size_t)m_base * KS + id] = wv;
}

// ---- load one wave's q-slice of S(t): rows j, bytes kg*32 ---------------
static __device__ __forceinline__ void load_S2(const unsigned char* Sbase, int j, int kg, intx8& sf) {
  const uint4* p = (const uint4*)(Sbase + (size_t)j * 128 + kg * 32);
  uint4 a = p[0], b = p[1];
  sf[0] = a.x; sf[1] = a.y; sf[2] = a.z; sf[3] = a.w;
  sf[4] = b.x; sf[5] = b.y; sf[6] = b.z; sf[7] = b.w;
}

// ---- 4-wave scan step: wave w owns MFMA q in {2w, 2w+1} (r5 structure) --
static __device__ __forceinline__ void scan_step4(
    int i, int L, int t, int t0s, int tLast, int n, int tid, int kg, int j0, int j1,
    const unsigned char* Ss, const float* wcomb, const float* emis, const float* emax,
    unsigned char* uL8, float* c0sh,
    intx8& uf, intx8& s0, intx8& s1, float& w0, float& w1, float& ex,
    float& M, float& pre_0, float& pre_1) {
  const float LNS = 8.317766167f;              // ln(4096)
  floatx4 cz = {0.f, 0.f, 0.f, 0.f};
  floatx4 d0 = __builtin_amdgcn_mfma_scale_f32_16x16x128_f8f6f4(
      uf, s0, cz, 0, 0, 0, 0x7F7F7F7F, 0, 0x7F7F7F7F);
  floatx4 d1 = __builtin_amdgcn_mfma_scale_f32_16x16x128_f8f6f4(
      uf, s1, cz, 0, 0, 0, 0x7F7F7F7F, 0, 0x7F7F7F7F);
  float cv0 = d0[0], cv1 = d1[0];
  // prefetch this wave's S(t+2) slice into the just-consumed regs
  int tp = t + 2; if (tp > tLast) tp = tLast;
  const unsigned char* Sp = Ss + (size_t)((tp - t0s) * 64 + n) * KK;
  load_S2(Sp, j0, kg, s0);
  load_S2(Sp, j1, kg, s1);
  if (tid == 0) *c0sh = cv0;                   // j0==0 on thread 0
  SBAR();                                      // c0 visible
  if (i < L - 1) {
    float c0 = *c0sh;
    float rc = fast_rcp(c0);
    float u0 = cv0 * w0 * rc, u1 = cv1 * w1 * rc;
    int pk0 = __builtin_amdgcn_cvt_pk_fp8_f32(u0, u0, 0, 0);
    int pk1 = __builtin_amdgcn_cvt_pk_fp8_f32(u1, u1, 0, 0);
    if (kg == 0) {
      uL8[j0] = (unsigned char)(pk0 & 0xff);
      uL8[j1] = (unsigned char)(pk1 & 0xff);
    }
    M += ex + __logf(c0) - LNS;                // wave-uniform, off u-chain
    // prefetch w/ex (t+2) — ride across barriers
    w0 = wcomb[(size_t)(tp * 64 + n) * KS + j0];
    w1 = wcomb[(size_t)(tp * 64 + n) * KS + j1];
    ex = emax[n * T_LEN + tp];
    SBAR();                                    // uL8(t+1) visible
    uint4 ua = *(const uint4*)&uL8[kg * 32];
    uint4 ub = *(const uint4*)&uL8[kg * 32 + 16];
    uf[0] = ua.x; uf[1] = ua.y; uf[2] = ua.z; uf[3] = ua.w;
    uf[4] = ub.x; uf[5] = ub.y; uf[6] = ub.z; uf[7] = ub.w;
  } else {
    float em0 = emis[(size_t)((n << 8) + tLast) * KS + j0];
    float em1 = emis[(size_t)((n << 8) + tLast) * KS + j1];
    pre_0 = M - LNS + __logf(cv0) + em0;
    pre_1 = M - LNS + __logf(cv1) + em1;
    SBAR();                                    // uniform barrier count
  }
}

// ---- FUSED kernel: blocks [0,64) = scan of chunk c-1 (4 waves/block);
//      blocks [64, 64+gx*32) = GEMM of chunk c (4 bys/block, 32 groups).
//      launch_bounds min-waves kept at 2: r6 showed (256,4) caps the
//      unified RF at 64 VGPR -> spills -> 2.8x regression. 128 VGPR +
//      33KB LDS already allows 4 blocks/CU without the declaration. ------
__global__ __launch_bounds__(256, 2) void k_fused(
    const unsigned short* exb, const unsigned short* trb,
    unsigned char* Sg, unsigned short* srowPh, int m_base, int Rcap,
    const unsigned char* Ss, const float* srowR, const float* wcomb,
    const float* emis, const float* emax, const float* pre0,
    float* alphaG, float* nll, int t0s, int tcs) {
  __shared__ alignas(16) unsigned short As[128 * 64];
  __shared__ alignas(16) unsigned short Bs[128 * 64];
  __shared__ alignas(16) unsigned char uL8[KS];
  __shared__ float c0sh;
  __shared__ float redW[4], redE[4];

  if (blockIdx.x < 64) {
    // -------- scan path: all 4 waves cooperate, uniform control flow -----
    if (tcs <= 0) return;
    int n = blockIdx.x;
    int tid = threadIdx.x;
    int w = tid >> 6, ln = tid & 63;
    int l15 = ln & 15, kg = ln >> 4;
    int q0 = w * 2;
    int j0 = q0 * 16 + l15, j1 = j0 + 16;
    const float SCALE = 4096.0f;
    int L = tcs, t1 = t0s + tcs, tLast = t1 - 1;
    const float* a0 = (t0s == 1) ? pre0 : (alphaG + (size_t)n * KS);
    float pre_0 = a0[j0], pre_1 = a0[j1];
    // cross-wave max for M
    float lm = fmaxf(pre_0, pre_1);
    #pragma unroll
    for (int s2 = 1; s2 < 16; s2 <<= 1) lm = fmaxf(lm, __shfl_xor(lm, s2));
    if (ln == 0) redW[w] = lm;
    SBAR();
    float M = fmaxf(fmaxf(redW[0], redW[1]), fmaxf(redW[2], redW[3]));
    // u(t0) from log-domain handoff
    {
      float r0 = srowR[(size_t)((t0s - 1) * 64 + n) * KS + j0];
      float r1 = srowR[(size_t)((t0s - 1) * 64 + n) * KS + j1];
      float u0 = __expf(pre_0 - M) * r0 * SCALE;
      float u1 = __expf(pre_1 - M) * r1 * SCALE;
      int pk0 = __builtin_amdgcn_cvt_pk_fp8_f32(u0, u0, 0, 0);
      int pk1 = __builtin_amdgcn_cvt_pk_fp8_f32(u1, u1, 0, 0);
      if (kg == 0) {
        uL8[j0] = (unsigned char)(pk0 & 0xff);
        uL8[j1] = (unsigned char)(pk1 & 0xff);
      }
    }
    SBAR();
    intx8 uf;
    {
      uint4 ua = *(const uint4*)&uL8[kg * 32];
      uint4 ub = *(const uint4*)&uL8[kg * 32 + 16];
      uf[0] = ua.x; uf[1] = ua.y; uf[2] = ua.z; uf[3] = ua.w;
      uf[4] = ub.x; uf[5] = ub.y; uf[6] = ub.z; uf[7] = ub.w;
    }
    // prime double-buffered per-wave state
    intx8 sA0, sA1, sB0, sB1;
    load_S2(Ss + (size_t)n * KK, j0, kg, sA0);
    load_S2(Ss + (size_t)n * KK, j1, kg, sA1);
    int iB = (L > 1) ? 1 : 0;
    const unsigned char* SpB = Ss + (size_t)(iB * 64 + n) * KK;
    load_S2(SpB, j0, kg, sB0);
    load_S2(SpB, j1, kg, sB1);
    int tB = t0s + iB;
    float wA0 = wcomb[(size_t)(t0s * 64 + n) * KS + j0];
    float wA1 = wcomb[(size_t)(t0s * 64 + n) * KS + j1];
    float wB0 = wcomb[(size_t)(tB * 64 + n) * KS + j0];
    float wB1 = wcomb[(size_t)(tB * 64 + n) * KS + j1];
    float exA = emax[n * T_LEN + t0s];
    float exB = emax[n * T_LEN + tB];
    int i = 0, t = t0s;
    for (;;) {
      scan_step4(i, L, t, t0s, tLast, n, tid, kg, j0, j1, Ss, wcomb, emis, emax,
                 uL8, &c0sh, uf, sA0, sA1, wA0, wA1, exA, M, pre_0, pre_1);
      if (++i >= L) break; ++t;
      scan_step4(i, L, t, t0s, tLast, n, tid, kg, j0, j1, Ss, wcomb, emis, emax,
                 uL8, &c0sh, uf, sB0, sB1, wB0, wB1, exB, M, pre_0, pre_1);
      if (++i >= L) break; ++t;
    }
    if (kg == 0) {
      alphaG[(size_t)n * KS + j0] = pre_0;
      alphaG[(size_t)n * KS + j1] = pre_1;
    }
    if (t1 == T_LEN) {
      float m2 = fmaxf(pre_0, pre_1);
      #pragma unroll
      for (int s2 = 1; s2 < 16; s2 <<= 1) m2 = fmaxf(m2, __shfl_xor(m2, s2));
      if (ln == 0) redW[w] = m2;
      SBAR();
      m2 = fmaxf(fmaxf(redW[0], redW[1]), fmaxf(redW[2], redW[3]));
      float le = __expf(pre_0 - m2) + __expf(pre_1 - m2);
      #pragma unroll
      for (int s2 = 1; s2 < 16; s2 <<= 1) le += __shfl_xor(le, s2);
      if (ln == 0) redE[w] = le;
      SBAR();
      if (tid == 0) nll[n] = m2 + __logf(redE[0] + redE[1] + redE[2] + redE[3]);
    }
    return;
  }

  // ---------------- GEMM path: 4 bys/block, 32 partial groups -----------
  int g = blockIdx.x - 64;
  int bx = g >> 5, grp = g & 31;
  int tid = threadIdx.x, wv = tid >> 6, ln = tid & 63;
  int wc = wv & 1, wm = wv >> 1;
  int m0 = m_base + bx * 128;
  int lr = ln & 15, lk = (ln >> 4) * 8;
  int lg = ln >> 4;
  floatx4 sacc[4][4] = {};
  for (int byi = 0; byi < 4; ++byi) {
    int by = grp * 4 + byi;
    int c0 = by * 128;
    floatx4 acc[4][4] = {};
    for (int k0 = 0; k0 < EDIM; k0 += 64) {
      #pragma unroll
      for (int r = 0; r < 4; ++r) {
        int chunk = (wv * 4 + r) * 64 + ln;
        int row = chunk >> 3, c8 = chunk & 7;
        gl_lds16(&exb[(size_t)(m0 + row) * EDIM + k0 + c8 * 8], &As[(wv * 4 + r) * 512]);
        gl_lds16(&trb[(size_t)(c0 + row) * EDIM + k0 + c8 * 8], &Bs[(wv * 4 + r) * 512]);
      }
      __syncthreads();                         // staging arrival (vmcnt drain)
      #pragma unroll
      for (int kk = 0; kk < 64; kk += 32) {
        int sw = ((((kk + lk) >> 3) ^ (lr & 7)) << 3);
        short8 af[4], bf[4];
        #pragma unroll
        for (int f = 0; f < 4; ++f)
          af[f] = *(const short8*)&As[(wm * 64 + f * 16 + lr) * 64 + sw];
        #pragma unroll
        for (int f = 0; f < 4; ++f)
          bf[f] = *(const short8*)&Bs[(wc * 64 + f * 16 + lr) * 64 + sw];
        #pragma unroll
        for (int fc = 0; fc < 4; ++fc)
          #pragma unroll
          for (int fm = 0; fm < 4; ++fm)
            acc[fc][fm] = __builtin_amdgcn_mfma_f32_16x16x32_bf16(bf[fc], af[fm], acc[fc][fm], 0, 0, 0);
      }
      LGKM_BARRIER();
    }
    unsigned char* Ts = (unsigned char*)As;
    #pragma unroll
    for (int fc = 0; fc < 4; ++fc) {
      #pragma unroll
      for (int fm = 0; fm < 4; ++fm) {
        floatx4 a = acc[fc][fm];
        float e0 = __expf(a[0]), e1 = __expf(a[1]), e2 = __expf(a[2]), e3 = __expf(a[3]);
        int pq = __builtin_amdgcn_cvt_pk_fp8_f32(e0, e1, 0, 0);
        pq = __builtin_amdgcn_cvt_pk_fp8_f32(e2, e3, pq, 1);
        int mloc = wm * 64 + fm * 16 + lr;
        int cl = wc * 64 + fc * 16 + lg * 4;
        *(int*)&Ts[mloc * 128 + (cl ^ ((mloc & 7) << 4))] = pq;
        sacc[fc][fm][0] += e0; sacc[fc][fm][1] += e1;
        sacc[fc][fm][2] += e2; sacc[fc][fm][3] += e3;
      }
    }
    LGKM_BARRIER();
    #pragma unroll
    for (int r = 0; r < 4; ++r) {
      int seg = r * 256 + tid;
      int mloc = seg >> 3, s = seg & 7;
      uint4 v = *(const uint4*)&Ts[mloc * 128 + ((s ^ (mloc & 7)) << 4)];
      *(uint4*)&Sg[(size_t)(bx * 128 + mloc) * KK + c0 + s * 16] = v;
    }
    LGKM_BARRIER();
  }
  // bf16 partial row-sums (32 groups, same bytes as 16 fp32 groups)
  #pragma unroll
  for (int fc = 0; fc < 4; ++fc) {
    #pragma unroll
    for (int fm = 0; fm < 4; ++fm) {
      int mloc = bx * 128 + wm * 64 + fm * 16 + lr;
      int i = wc * 64 + fc * 16 + lg * 4;
      ushort4 h;
      h.x = f2bf(sacc[fc][fm][0]); h.y = f2bf(sacc[fc][fm][1]);
      h.z = f2bf(sacc[fc][fm][2]); h.w = f2bf(sacc[fc][fm][3]);
      *(ushort4*)&srowPh[((size_t)grp * Rcap + mloc) * KS + i] = h;
    }
  }
}

// ---------------- final: out = -mean(nll) --------------------------------
__global__ __launch_bounds__(64) void k_final(const float* nll, float* out) {
  int tid = threadIdx.x;
  float v = nll[tid];
  #pragma unroll
  for (int s = 1; s < 64; s <<= 1) v += __shfl_xor(v, s);
  if (tid == 0) out[0] = -v / 64.0f;
}

extern "C" void kernel_launch(void* const* d_in, const int* in_sizes, int n_in,
                              void* d_out, int out_size, void* d_ws, size_t ws_size,
                              hipStream_t stream) {
  const int*   x       = (const int*)d_in[0];
  const float* embed_w = (const float*)d_in[1];
  const float* trans_w = (const float*)d_in[2];
  const float* start_w = (const float*)d_in[3];
  const float* start_b = (const float*)d_in[4];
  const float* ecl     = (const float*)d_in[5];
  const float* emw     = (const float*)d_in[6];

  char* w = (char*)d_ws;
  size_t off = 0;
  auto alloc = [&](size_t bytes) -> char* {
    char* p = w + off;
    off = (off + bytes + 255) & ~(size_t)255;
    return p;
  };
  float*          pre0   = (float*)alloc(KS * 4);
  float*          lseC   = (float*)alloc(KS * 4);
  float*          nll    = (float*)alloc(N_SEQ * 4);
  float*          alphaG = (float*)alloc((size_t)N_SEQ * KS * 4);
  float*          emax   = (float*)alloc((size_t)N_SEQ * T_LEN * 4);
  unsigned short* trb    = (unsigned short*)alloc((size_t)KK * EDIM * 2);
  unsigned short* exb    = (unsigned short*)alloc((size_t)MROWS * EDIM * 2);
  float*          emis   = (float*)alloc((size_t)N_SEQ * T_LEN * KS * 4);
  float*          srowR  = (float*)alloc((size_t)MROWS * KS * 4);
  float*          wcomb  = (float*)alloc((size_t)MROWS * KS * 4);
  // region: S double buffer + srowPh; transient C aliases region start
  char* region = w + off;
  size_t avail = (ws_size > off) ? (ws_size - off) : 0;
  float* C = (float*)region;

  // per chunk: R = Tc*64 rows; need 2*R*16384 (S dbuf) + R*8192 (srowPh:
  // 32 groups x 128 x bf16 = 8192 B/row — same budget as before)
  int Tc = 2;
  for (int c = 2; c <= 64; c += 2)
    if ((size_t)c * 64 * 40960 <= avail) Tc = c;
  int Rcap = Tc * 64;
  unsigned char*  S0     = (unsigned char*)region;
  unsigned char*  S1     = (unsigned char*)(region + (size_t)Rcap * KK);
  unsigned short* srowPh = (unsigned short*)(region + (size_t)2 * Rcap * KK);

  hipLaunchKernelGGL(k_prep,       dim3(1),        dim3(128), 0, stream, start_w, start_b, pre0);
  hipLaunchKernelGGL(k_transcvt,   dim3(4096),     dim3(256), 0, stream, trans_w, trb);
  hipLaunchKernelGGL(k_embed,      dim3(16384),    dim3(256), 0, stream, x, embed_w, exb);
  hipLaunchKernelGGL(k_emitlogits, dim3(500, 2),   dim3(256), 0, stream, ecl, emw, C);
  hipLaunchKernelGGL(k_lsec,       dim3(128),      dim3(256), 0, stream, C, lseC);
  hipLaunchKernelGGL(k_emis,       dim3(255, 64),  dim3(128), 0, stream, x, C, lseC, emis, emax);

  // chunk table
  int ct0[140], ctc[140], nc = 0;
  {
    int t0 = 1;
    while (t0 < T_LEN) {
      int tc = T_LEN - t0; if (tc > Tc) tc = Tc;
      ct0[nc] = t0; ctc[nc] = tc; ++nc; t0 += tc;
    }
  }
  // pipeline: fused_c = gemm(chunk c) + scan(chunk c-1); then comb(c)
  for (int c = 0; c <= nc; ++c) {
    bool hasG = (c < nc), hasS = (c > 0);
    int gx = 0, m_base = 0;
    if (hasG) { gx = (ctc[c] * 64 + 127) / 128; m_base = (ct0[c] - 1) * 64; }
    unsigned char* Sg = (c & 1) ? S1 : S0;
    unsigned char* Ssc = ((c - 1) & 1) ? S1 : S0;
    int t0s = hasS ? ct0[c - 1] : 0;
    int tcs = hasS ? ctc[c - 1] : 0;
    hipLaunchKernelGGL(k_fused, dim3(64 + gx * 32), dim3(256), 0, stream,
                       exb, trb, Sg, srowPh, m_base, Rcap,
                       Ssc, srowR, wcomb, emis, emax, pre0, alphaG, nll, t0s, tcs);
    if (hasG)
      hipLaunchKernelGGL(k_comb, dim3(gx * 64), dim3(256), 0, stream,
                         srowPh, srowR, wcomb, emis, emax, m_base, Rcap, gx * 128);
  }
  hipLaunchKernelGGL(k_final, dim3(1), dim3(64), 0, stream, nll, (float*)d_out);
}